// Round 7
// baseline (277.791 us; speedup 1.0000x reference)
//
#include <hip/hip_runtime.h>
#include <hip/hip_bf16.h>

#define L_SEQ 2048
#define DMODEL 1024
#define NHEAD 16
#define DHEAD 64
#define D3 3072

typedef __attribute__((ext_vector_type(8))) short s8v;   // 8 bf16 (4 VGPRs)
typedef __attribute__((ext_vector_type(4))) float f4v;   // MFMA acc
typedef unsigned int u32;
#define AS1 __attribute__((address_space(1)))
#define AS3 __attribute__((address_space(3)))

__device__ __forceinline__ short f2bf(float f) {
  __hip_bfloat16 h = __float2bfloat16(f);
  return *reinterpret_cast<short*>(&h);
}
__device__ __forceinline__ float bf2f(short s) {
  return __uint_as_float(((u32)(unsigned short)s) << 16);
}
__device__ __forceinline__ int pack2bf(float lo, float hi) {
  return (int)(((unsigned)(unsigned short)f2bf(hi) << 16) |
               (unsigned)(unsigned short)f2bf(lo));
}

// ---------------- x -> bf16 (row-major) -------------------------------------
__global__ __launch_bounds__(256) void conv_x(const float* __restrict__ x,
                                              short* __restrict__ xb)
{
  int i = (blockIdx.x * 256 + threadIdx.x) * 4;
  float4 v = *(const float4*)(x + i);
  short4 o;
  o.x = f2bf(v.x); o.y = f2bf(v.y); o.z = f2bf(v.z); o.w = f2bf(v.w);
  *(short4*)(xb + i) = o;
}

// ---------------- W (K x N fp32) -> W^T (N x K bf16) ------------------------
__global__ __launch_bounds__(256) void transpose_conv(const float* __restrict__ W,
    short* __restrict__ Wt, int K, int N)
{
  __shared__ float T[32][33];
  int bx = blockIdx.x, by = blockIdx.y;
  int col = threadIdx.x & 31, rb = threadIdx.x >> 5;
  #pragma unroll
  for (int it = 0; it < 4; ++it) {
    int r = it * 8 + rb;
    T[r][col] = W[(size_t)(by * 32 + r) * N + bx * 32 + col];
  }
  __syncthreads();
  #pragma unroll
  for (int it = 0; it < 4; ++it) {
    int r = it * 8 + rb;
    Wt[(size_t)(bx * 32 + r) * K + by * 32 + col] = f2bf(T[col][r]);
  }
}

// ---------------- Vf (L,1024) fp32 -> Vtb (H,64,L) bf16 ---------------------
__global__ __launch_bounds__(256) void conv_vt(const float* __restrict__ Vf,
                                               short* __restrict__ Vtb)
{
  int kb = blockIdx.x, h = blockIdx.y;
  int tid = threadIdx.x;
  __shared__ float Vs[64][65];
  for (int idx = tid; idx < 2048; idx += 256) {
    int key = idx >> 5, e2 = idx & 31;
    float2 vv = *(const float2*)(Vf + (size_t)(kb * 64 + key) * 1024 + h * 64 + e2 * 2);
    Vs[key][e2 * 2] = vv.x; Vs[key][e2 * 2 + 1] = vv.y;
  }
  __syncthreads();
  for (int idx = tid; idx < 2048; idx += 256) {
    int dim = idx >> 5, k2 = idx & 31;
    *(int*)&Vtb[((size_t)h * 64 + dim) * 2048 + kb * 64 + k2 * 2] =
        pack2bf(Vs[k2 * 2][dim], Vs[k2 * 2 + 1][dim]);
  }
}

// ---------------- bf16 MFMA GEMM, double-buffered prefetch ------------------
// MODE 0: C = A@B + bias (fp32 out, stride N)
// MODE 2: fused qkv+gate: n<1024 -> Qb bf16; n<2048 -> Kb bf16;
//         n<3072 -> Vf fp32 (L,1024); else GELU(.+bias2) -> bf16 C2 (gate)
template<int BM, int BN, int MODE>
__global__ __launch_bounds__(256) void gemm_mfma(
    const short* __restrict__ A, const short* __restrict__ Bt,
    const float* __restrict__ bias, const float* __restrict__ bias2,
    float* __restrict__ C, short* __restrict__ C2,
    short* __restrict__ QbP, short* __restrict__ KbP,
    int M, int N, int K)
{
  constexpr int LA = BM / 64, LB = BN / 64;
  constexpr int WM = BM / 2, WN = BN / 2;
  constexpr int MT = WM / 16, NT = WN / 16;
  __shared__ __align__(16) short As[2][BM * 32];
  __shared__ __align__(16) short Bs[2][BN * 32];
  const int tid = threadIdx.x;
  const int w = tid >> 6, lane = tid & 63;
  const int quad = lane >> 4, c = lane & 15;
  const int m0 = blockIdx.y * BM, n0 = blockIdx.x * BN;
  const int wm = (w & 1) * WM, wn = (w >> 1) * WN;
  f4v acc[MT][NT] = {};

  auto stage = [&](int buf, int k0) {
    #pragma unroll
    for (int it = 0; it < LA; ++it) {
      int off = (it * 256 + tid) * 16;
      int row = off >> 6, colh = (off & 63) >> 1;
      __builtin_amdgcn_global_load_lds(
          (const AS1 u32*)(A + (size_t)(m0 + row) * K + k0 + colh),
          (AS3 u32*)(&As[buf][0] + (off >> 1)), 16, 0, 0);
    }
    #pragma unroll
    for (int it = 0; it < LB; ++it) {
      int off = (it * 256 + tid) * 16;
      int row = off >> 6, colh = (off & 63) >> 1;
      __builtin_amdgcn_global_load_lds(
          (const AS1 u32*)(Bt + (size_t)(n0 + row) * K + k0 + colh),
          (AS3 u32*)(&Bs[buf][0] + (off >> 1)), 16, 0, 0);
    }
  };
  stage(0, 0);
  int cur = 0;
  for (int k0 = 0; k0 < K; k0 += 32) {
    __syncthreads();
    if (k0 + 32 < K) stage(cur ^ 1, k0 + 32);
    s8v af[MT], bf[NT];
    #pragma unroll
    for (int mt = 0; mt < MT; ++mt)
      af[mt] = *(s8v*)&As[cur][(wm + mt * 16 + c) * 32 + quad * 8];
    #pragma unroll
    for (int nt = 0; nt < NT; ++nt)
      bf[nt] = *(s8v*)&Bs[cur][(wn + nt * 16 + c) * 32 + quad * 8];
    #pragma unroll
    for (int mt = 0; mt < MT; ++mt)
      #pragma unroll
      for (int nt = 0; nt < NT; ++nt)
        acc[mt][nt] = __builtin_amdgcn_mfma_f32_16x16x32_bf16(
            af[mt], bf[nt], acc[mt][nt], 0, 0, 0);
    cur ^= 1;
  }
  #pragma unroll
  for (int mt = 0; mt < MT; ++mt)
    #pragma unroll
    for (int r = 0; r < 4; ++r) {
      int m = m0 + wm + mt * 16 + quad * 4 + r;
      #pragma unroll
      for (int nt = 0; nt < NT; ++nt) {
        int n = n0 + wn + nt * 16 + c;
        float v = acc[mt][nt][r];
        if (MODE == 0) {
          C[(size_t)m * N + n] = v + bias[n];
        } else {
          if (n < 2048) {
            float v2 = v + bias[n];
            int hh = (n >> 6) & 15, ee = n & 63;
            short* dst = (n < 1024) ? QbP : KbP;
            dst[((size_t)hh * 2048 + m) * 64 + ee] = f2bf(v2);
          } else if (n < 3072) {
            C[(size_t)m * 1024 + (n - 2048)] = v + bias[n];
          } else {
            float t = v + bias2[n - 3072];
            t = 0.5f * t * (1.0f + erff(t * 0.70710678118654752f));
            C2[(size_t)m * 512 + (n - 3072)] = f2bf(t);
          }
        }
      }
    }
}

// ---------------- flash attention, key-split, un-normalized partials --------
// 768 blocks, LPT order. Emits O~ (no 1/l), m, l per query.
__global__ __launch_bounds__(256) void attn_mfma(
    const short* __restrict__ Qb, const short* __restrict__ Kb,
    const short* __restrict__ Vtb, float* __restrict__ O0,
    float* __restrict__ O1, float* __restrict__ ml)
{
  const int bid = blockIdx.x;
  int h, qt, ts, te;
  float *Odst, *mdst, *ldst;
  if (bid < 512) {                       // qt 31..16, split in 2 parts, big first
    qt = 31 - (bid >> 5);
    int r = bid & 31; h = r >> 1;
    int n = qt + 1, n2 = (n + 1) >> 1;
    if ((r & 1) == 0) {
      ts = 0; te = n2;
      int s = h * 32 + qt;
      Odst = O0 + (size_t)s * 4096; mdst = ml + s * 64; ldst = ml + 32768 + s * 64;
    } else {
      ts = n2; te = n;
      int s = h * 16 + (qt - 16);
      Odst = O1 + (size_t)s * 4096; mdst = ml + 65536 + s * 64; ldst = ml + 81920 + s * 64;
    }
  } else {                               // qt 15..0, unsplit
    int r = bid - 512; qt = 15 - (r >> 4); h = r & 15; ts = 0; te = qt + 1;
    int s = h * 32 + qt;
    Odst = O0 + (size_t)s * 4096; mdst = ml + s * 64; ldst = ml + 32768 + s * 64;
  }
  const int q0 = qt * 64;
  const int tid = threadIdx.x;
  const int w = tid >> 6, lane = tid & 63;
  const int quad = lane >> 4, c = lane & 15;

  __shared__ __align__(16) char smem[27648];
  short* Ks = (short*)smem;            // [key][dim] stride 72
  short* Vt = Ks + 4608;               // [dim][key] stride 72
  short* Ps = Vt + 4608;               // [wave][16][72]
  float* Ob = (float*)smem;            // [64][66] overlay

  const int qrow = q0 + w * 16 + c;
  s8v qf[2];
  qf[0] = *(const s8v*)(Qb + ((size_t)h * 2048 + qrow) * 64 + quad * 8);
  qf[1] = *(const s8v*)(Qb + ((size_t)h * 2048 + qrow) * 64 + 32 + quad * 8);

  const int srow = tid >> 3, sc = (tid & 7) * 8;
  int4 pk0, pk1, pv0, pv1;
  auto load_tile = [&](int t0) {
    const short* kbase = Kb + ((size_t)h * 2048 + t0 * 64) * 64;
    const short* vbase = Vtb + (size_t)h * 64 * 2048 + t0 * 64;
    pk0 = *(const int4*)(kbase + (size_t)srow * 64 + sc);
    pk1 = *(const int4*)(kbase + (size_t)(srow + 32) * 64 + sc);
    pv0 = *(const int4*)(vbase + (size_t)srow * 2048 + sc);
    pv1 = *(const int4*)(vbase + (size_t)(srow + 32) * 2048 + sc);
  };
  load_tile(ts);

  f4v o_acc[4] = {};
  float m = -1e30f, l = 0.f;

  for (int t0 = ts; t0 < te; ++t0) {
    __syncthreads();
    *(int4*)&Ks[srow * 72 + sc] = pk0;
    *(int4*)&Ks[(srow + 32) * 72 + sc] = pk1;
    *(int4*)&Vt[srow * 72 + sc] = pv0;
    *(int4*)&Vt[(srow + 32) * 72 + sc] = pv1;
    __syncthreads();
    if (t0 + 1 < te) load_tile(t0 + 1);

    f4v s_acc[4] = {};
    #pragma unroll
    for (int kt = 0; kt < 4; ++kt) {
      #pragma unroll
      for (int kc = 0; kc < 2; ++kc) {
        s8v kf = *(s8v*)&Ks[(kt * 16 + c) * 72 + kc * 32 + quad * 8];
        s_acc[kt] = __builtin_amdgcn_mfma_f32_16x16x32_bf16(kf, qf[kc], s_acc[kt], 0, 0, 0);
      }
    }
    float sv[4][4];
    bool full = (t0 * 64 + 63) <= (q0 + w * 16);
    #pragma unroll
    for (int kt = 0; kt < 4; ++kt)
      #pragma unroll
      for (int r = 0; r < 4; ++r) {
        float s = s_acc[kt][r] * 0.125f;
        if (!full) {
          int key = t0 * 64 + kt * 16 + quad * 4 + r;
          s = (key <= qrow) ? s : -1e30f;
        }
        sv[kt][r] = s;
      }
    float mloc = -1e30f;
    #pragma unroll
    for (int kt = 0; kt < 4; ++kt)
      #pragma unroll
      for (int r = 0; r < 4; ++r) mloc = fmaxf(mloc, sv[kt][r]);
    mloc = fmaxf(mloc, __shfl_xor(mloc, 16));
    mloc = fmaxf(mloc, __shfl_xor(mloc, 32));
    float mnew = fmaxf(fmaxf(m, mloc), -1e20f);   // clamp: all-masked rows safe
    float alpha = __expf(m - mnew);
    m = mnew;
    float p[4][4], ls = 0.f;
    #pragma unroll
    for (int kt = 0; kt < 4; ++kt)
      #pragma unroll
      for (int r = 0; r < 4; ++r) { p[kt][r] = __expf(sv[kt][r] - mnew); ls += p[kt][r]; }
    ls += __shfl_xor(ls, 16);
    ls += __shfl_xor(ls, 32);
    l = l * alpha + ls;
    #pragma unroll
    for (int mt = 0; mt < 4; ++mt)
      #pragma unroll
      for (int r = 0; r < 4; ++r) o_acc[mt][r] *= alpha;
    short* Pw = Ps + w * 1152;
    #pragma unroll
    for (int kt = 0; kt < 4; ++kt) {
      *(int*)&Pw[c * 72 + kt * 16 + quad * 4]     = pack2bf(p[kt][0], p[kt][1]);
      *(int*)&Pw[c * 72 + kt * 16 + quad * 4 + 2] = pack2bf(p[kt][2], p[kt][3]);
    }
    #pragma unroll
    for (int kc2 = 0; kc2 < 2; ++kc2) {
      s8v pf = *(s8v*)&Pw[c * 72 + kc2 * 32 + quad * 8];
      #pragma unroll
      for (int mt = 0; mt < 4; ++mt) {
        s8v vf = *(s8v*)&Vt[(mt * 16 + c) * 72 + kc2 * 32 + quad * 8];
        o_acc[mt] = __builtin_amdgcn_mfma_f32_16x16x32_bf16(vf, pf, o_acc[mt], 0, 0, 0);
      }
    }
  }

  __syncthreads();
  #pragma unroll
  for (int mt = 0; mt < 4; ++mt)
    #pragma unroll
    for (int r = 0; r < 4; ++r)
      Ob[(w * 16 + c) * 66 + mt * 16 + quad * 4 + r] = o_acc[mt][r];
  if (quad == 0) { mdst[w * 16 + c] = m; ldst[w * 16 + c] = l; }
  __syncthreads();
  for (int i = tid; i < 4096; i += 256)
    Odst[i] = Ob[(i >> 6) * 66 + (i & 63)];
}

// ---------------- merge partials + gate + combine -> ycb bf16 (L,D) ---------
__global__ __launch_bounds__(256) void attn_merge(
    const float* __restrict__ O0, const float* __restrict__ O1,
    const float* __restrict__ ml, const float* __restrict__ ystp,
    const float* __restrict__ alpha, short* __restrict__ ycb)
{
  int bid = blockIdx.x;
  int h = bid >> 5, qt = bid & 31;
  int slot0 = h * 32 + qt;
  int tid = threadIdx.x;
  for (int it = 0; it < 16; ++it) {
    int idx = it * 256 + tid;
    int q = idx >> 6, e = idx & 63;
    int gq = qt * 64 + q;
    float oo = O0[(size_t)slot0 * 4096 + idx];
    float m0v = ml[slot0 * 64 + q], l0v = ml[32768 + slot0 * 64 + q];
    float ll;
    if (qt >= 16) {
      int slot1 = h * 16 + (qt - 16);
      float o1 = O1[(size_t)slot1 * 4096 + idx];
      float m1v = ml[65536 + slot1 * 64 + q], l1v = ml[81920 + slot1 * 64 + q];
      float ms = fmaxf(m0v, m1v);
      float w0 = __expf(m0v - ms), w1 = __expf(m1v - ms);
      oo = oo * w0 + o1 * w1;
      ll = l0v * w0 + l1v * w1;
    } else {
      ll = l0v;
    }
    float ys = oo / ll;
    float a = alpha[gq * 16 + h];
    float yst = ystp[((size_t)h * 2048 + gq) * 64 + e];
    ycb[(size_t)gq * 1024 + h * 64 + e] = f2bf(a * ys + (1.f - a) * yst);
  }
}

// ---------------- STP branch (bf16 K/Q inputs, fp32 V) ----------------------
__global__ __launch_bounds__(256) void stp_local(const float* __restrict__ Vf,
    const short* __restrict__ Kb, const float* __restrict__ Lam,
    const float* __restrict__ Gam, float* __restrict__ states)
{
  int c = blockIdx.x, h = blockIdx.y;
  int tid = threadIdx.x;
  int i = tid >> 2, j0 = (tid & 3) * 16;
  __shared__ float Kc[64][64];
  __shared__ float Vc[64][64];
  for (int idx = tid; idx < 1024; idx += 256) {
    int t = idx >> 4, e4 = (idx & 15) * 4;
    short4 ks = *(const short4*)(Kb + ((size_t)h * 2048 + c * 64 + t) * 64 + e4);
    Kc[t][e4]     = bf2f(ks.x) * 0.125f;
    Kc[t][e4 + 1] = bf2f(ks.y) * 0.125f;
    Kc[t][e4 + 2] = bf2f(ks.z) * 0.125f;
    Kc[t][e4 + 3] = bf2f(ks.w) * 0.125f;
    float4 vv = *(const float4*)(Vf + (size_t)(c * 64 + t) * 1024 + h * 64 + e4);
    Vc[t][e4] = vv.x; Vc[t][e4 + 1] = vv.y; Vc[t][e4 + 2] = vv.z; Vc[t][e4 + 3] = vv.w;
  }
  float r[16], g[16], s[16];
  #pragma unroll
  for (int e = 0; e < 16; ++e) {
    int idx = h * 4096 + i * 64 + j0 + e;
    r[e] = 1.f / (1.f + expf(Lam[idx]));
    g[e] = Gam[idx];
    s[e] = 0.f;
  }
  __syncthreads();
  for (int t = 0; t < 64; ++t) {
    float v = Vc[t][i];
    #pragma unroll
    for (int e = 0; e < 16; ++e)
      s[e] = r[e] * s[e] + g[e] * (v * Kc[t][j0 + e]);
  }
  #pragma unroll
  for (int e = 0; e < 16; ++e)
    states[((size_t)h * 32 + c) * 4096 + i * 64 + j0 + e] = s[e];
}

__global__ __launch_bounds__(256) void stp_scan(const float* __restrict__ Lam,
                                                float* __restrict__ states)
{
  int gid = blockIdx.x * 256 + threadIdx.x;
  float r = 1.f / (1.f + expf(Lam[gid]));
  float r64 = r;
  #pragma unroll
  for (int q = 0; q < 6; ++q) r64 *= r64;
  int h = gid >> 12, low = gid & 4095;
  float acc = 0.f;
  for (int c = 0; c < 32; ++c) {
    size_t idx = ((size_t)h * 32 + c) * 4096 + low;
    float dloc = states[idx];
    states[idx] = acc;
    acc = r64 * acc + dloc;
  }
}

__global__ __launch_bounds__(256) void stp_out(const float* __restrict__ Vf,
    const short* __restrict__ Kb, const short* __restrict__ Qb,
    const float* __restrict__ Lam, const float* __restrict__ Gam,
    const float* __restrict__ Wst, const float* __restrict__ states,
    float* __restrict__ ystp)
{
  int c = blockIdx.x, h = blockIdx.y;
  int tid = threadIdx.x;
  int i = tid >> 2, j0 = (tid & 3) * 16;
  __shared__ float Kc[64][64];
  __shared__ float Vc[64][64];
  __shared__ float Qc[64][64];
  for (int idx = tid; idx < 1024; idx += 256) {
    int t = idx >> 4, e4 = (idx & 15) * 4;
    size_t bo = ((size_t)h * 2048 + c * 64 + t) * 64 + e4;
    short4 ks = *(const short4*)(Kb + bo);
    short4 qs = *(const short4*)(Qb + bo);
    Kc[t][e4]     = bf2f(ks.x) * 0.125f;
    Kc[t][e4 + 1] = bf2f(ks.y) * 0.125f;
    Kc[t][e4 + 2] = bf2f(ks.z) * 0.125f;
    Kc[t][e4 + 3] = bf2f(ks.w) * 0.125f;
    Qc[t][e4]     = bf2f(qs.x);
    Qc[t][e4 + 1] = bf2f(qs.y);
    Qc[t][e4 + 2] = bf2f(qs.z);
    Qc[t][e4 + 3] = bf2f(qs.w);
    float4 vv = *(const float4*)(Vf + (size_t)(c * 64 + t) * 1024 + h * 64 + e4);
    Vc[t][e4] = vv.x; Vc[t][e4 + 1] = vv.y; Vc[t][e4 + 2] = vv.z; Vc[t][e4 + 3] = vv.w;
  }
  float r[16], g[16], s[16], w[16];
  #pragma unroll
  for (int e = 0; e < 16; ++e) {
    int idx = h * 4096 + i * 64 + j0 + e;
    r[e] = 1.f / (1.f + expf(Lam[idx]));
    g[e] = Gam[idx];
    w[e] = Wst[idx];
    s[e] = states[((size_t)h * 32 + c) * 4096 + i * 64 + j0 + e];
  }
  __syncthreads();
  for (int t = 0; t < 64; ++t) {
    float v = Vc[t][i];
    float y = 0.f;
    #pragma unroll
    for (int e = 0; e < 16; ++e) {
      s[e] = r[e] * s[e] + g[e] * (v * Kc[t][j0 + e]);
      y += (w[e] + s[e]) * Qc[t][j0 + e];
    }
    y += __shfl_xor(y, 1);
    y += __shfl_xor(y, 2);
    if ((tid & 3) == 0)
      ystp[((size_t)h * L_SEQ + c * 64 + t) * 64 + i] = y;
  }
}

// ---------------- gate tail (bf16 g) ----------------------------------------
__global__ __launch_bounds__(256) void gate2_kernel(const short* __restrict__ g_bf,
    const float* __restrict__ w2, const float* __restrict__ b2,
    float* __restrict__ alpha)
{
  int gid = blockIdx.x * 256 + threadIdx.x;
  int l = gid >> 4, h = gid & 15;
  float acc = b2[h];
  const short* grow = g_bf + (size_t)l * 512;
  for (int c2 = 0; c2 < 512; c2 += 2) {
    u32 pk = *(const u32*)(grow + c2);
    float g0 = __uint_as_float(pk << 16);
    float g1 = __uint_as_float(pk & 0xffff0000u);
    acc += g0 * w2[c2 * 16 + h] + g1 * w2[(c2 + 1) * 16 + h];
  }
  alpha[gid] = 1.f / (1.f + expf(-acc));
}

extern "C" void kernel_launch(void* const* d_in, const int* in_sizes, int n_in,
                              void* d_out, int out_size, void* d_ws, size_t ws_size,
                              hipStream_t stream) {
  (void)in_sizes; (void)n_in; (void)out_size; (void)ws_size;
  const float* x      = (const float*)d_in[0];
  const float* Wqkv_w = (const float*)d_in[1];
  const float* Wqkv_b = (const float*)d_in[2];
  const float* out_w  = (const float*)d_in[3];
  const float* out_b  = (const float*)d_in[4];
  const float* W_st   = (const float*)d_in[5];
  const float* Lam    = (const float*)d_in[6];
  const float* Gam    = (const float*)d_in[7];
  const float* gw1    = (const float*)d_in[8];
  const float* gb1    = (const float*)d_in[9];
  const float* gw2    = (const float*)d_in[10];
  const float* gb2    = (const float*)d_in[11];

  float* ws     = (float*)d_ws;
  float* Vf     = ws;                        // (L,1024) fp32        2097152 f
  float* O0buf  = ws + 2097152;              // 512 slots x 4096     2097152 f
  float* ystp   = ws + 4194304;              //                      2097152 f
  float* states = ws + 6291456;              // stp states; later: [0,1048576) O1, [1048576,2097152) ycb
  float* ovl    = ws + 8388608;              // overlay span         3670016 f
  float* alpha  = ws + 12058624;             //                        32768 f
  float* ml     = ws + 12091392;             // m0/l0/m1/l1            98304 f
  short* Qb     = (short*)(ws + 12189696);   // (H,L,64) bf16        1048576 f
  short* Kb     = Qb + 2097152;              //                      1048576 f
  // total: 14286848 floats = 57.1 MB
  // phase-1 overlay
  short* xb     = (short*)ovl;                      // (L,D) bf16
  short* wt_buf = (short*)(ovl + 1048576);          // 3584x1024 bf16
  short* g_bf   = (short*)(ovl + 2883584);          // 2048x512 bf16
  // phase-2/3 overlay
  short* Vtb    = (short*)ovl;                      // (H,64,L) bf16 (xb dead)
  short* wtO    = (short*)ovl;                      // out_w^T (Vtb dead)
  float* O1buf  = states;                           // first half (stp done)
  short* ycb    = (short*)(states + 1048576);       // second half

  // phase 1: fused qkv+gate projection (emits Qb/Kb bf16, Vf fp32, g_bf)
  conv_x<<<dim3(2048), 256, 0, stream>>>(x, xb);
  transpose_conv<<<dim3(96, 32), 256, 0, stream>>>(Wqkv_w, wt_buf, 1024, 3072);
  transpose_conv<<<dim3(16, 32), 256, 0, stream>>>(gw1, wt_buf + 3072 * 1024, 1024, 512);
  gemm_mfma<128, 128, 2><<<dim3(28, 16), 256, 0, stream>>>(
      xb, wt_buf, Wqkv_b, gb1, Vf, g_bf, Qb, Kb, 2048, 3584, 1024);
  gate2_kernel<<<dim3(128), 256, 0, stream>>>(g_bf, gw2, gb2, alpha);
  // STP branch
  stp_local<<<dim3(32, 16), 256, 0, stream>>>(Vf, Kb, Lam, Gam, states);
  stp_scan<<<dim3(256), 256, 0, stream>>>(Lam, states);
  stp_out<<<dim3(32, 16), 256, 0, stream>>>(Vf, Kb, Qb, Lam, Gam, W_st, states, ystp);
  // phase 2: attention (key-split) + merge/gate/combine
  conv_vt<<<dim3(32, 16), 256, 0, stream>>>(Vf, Vtb);
  attn_mfma<<<dim3(768), 256, 0, stream>>>(Qb, Kb, Vtb, O0buf, O1buf, ml);
  attn_merge<<<dim3(512), 256, 0, stream>>>(O0buf, O1buf, ml, ystp, alpha, ycb);
  // phase 3: out projection
  transpose_conv<<<dim3(32, 32), 256, 0, stream>>>(out_w, wtO, 1024, 1024);
  gemm_mfma<64, 128, 0><<<dim3(8, 32), 256, 0, stream>>>(
      ycb, wtO, out_b, nullptr, (float*)d_out, nullptr, nullptr, nullptr, 2048, 1024, 1024);
}

// Round 8
// 264.109 us; speedup vs baseline: 1.0518x; 1.0518x over previous
//
#include <hip/hip_runtime.h>
#include <hip/hip_bf16.h>

#define L_SEQ 2048
#define DMODEL 1024
#define NHEAD 16
#define DHEAD 64
#define D3 3072

typedef __attribute__((ext_vector_type(8))) short s8v;   // 8 bf16 (4 VGPRs)
typedef __attribute__((ext_vector_type(4))) float f4v;   // MFMA acc
typedef unsigned int u32;
#define AS1 __attribute__((address_space(1)))
#define AS3 __attribute__((address_space(3)))

__device__ __forceinline__ short f2bf(float f) {
  __hip_bfloat16 h = __float2bfloat16(f);
  return *reinterpret_cast<short*>(&h);
}
__device__ __forceinline__ float bf2f(short s) {
  return __uint_as_float(((u32)(unsigned short)s) << 16);
}
__device__ __forceinline__ int pack2bf(float lo, float hi) {
  return (int)(((unsigned)(unsigned short)f2bf(hi) << 16) |
               (unsigned)(unsigned short)f2bf(lo));
}

// ---------------- x -> bf16 (row-major) -------------------------------------
__global__ __launch_bounds__(256) void conv_x(const float* __restrict__ x,
                                              short* __restrict__ xb)
{
  int i = (blockIdx.x * 256 + threadIdx.x) * 4;
  float4 v = *(const float4*)(x + i);
  short4 o;
  o.x = f2bf(v.x); o.y = f2bf(v.y); o.z = f2bf(v.z); o.w = f2bf(v.w);
  *(short4*)(xb + i) = o;
}

// ---------------- W (K x N fp32) -> W^T (N x K bf16) ------------------------
__global__ __launch_bounds__(256) void transpose_conv(const float* __restrict__ W,
    short* __restrict__ Wt, int K, int N)
{
  __shared__ float T[32][33];
  int bx = blockIdx.x, by = blockIdx.y;
  int col = threadIdx.x & 31, rb = threadIdx.x >> 5;
  #pragma unroll
  for (int it = 0; it < 4; ++it) {
    int r = it * 8 + rb;
    T[r][col] = W[(size_t)(by * 32 + r) * N + bx * 32 + col];
  }
  __syncthreads();
  #pragma unroll
  for (int it = 0; it < 4; ++it) {
    int r = it * 8 + rb;
    Wt[(size_t)(bx * 32 + r) * K + by * 32 + col] = f2bf(T[col][r]);
  }
}

// ---------------- Vf (L,1024) fp32 -> Vtb (H,64,L) bf16 ---------------------
__global__ __launch_bounds__(256) void conv_vt(const float* __restrict__ Vf,
                                               short* __restrict__ Vtb)
{
  int kb = blockIdx.x, h = blockIdx.y;
  int tid = threadIdx.x;
  __shared__ float Vs[64][65];
  for (int idx = tid; idx < 2048; idx += 256) {
    int key = idx >> 5, e2 = idx & 31;
    float2 vv = *(const float2*)(Vf + (size_t)(kb * 64 + key) * 1024 + h * 64 + e2 * 2);
    Vs[key][e2 * 2] = vv.x; Vs[key][e2 * 2 + 1] = vv.y;
  }
  __syncthreads();
  for (int idx = tid; idx < 2048; idx += 256) {
    int dim = idx >> 5, k2 = idx & 31;
    *(int*)&Vtb[((size_t)h * 64 + dim) * 2048 + kb * 64 + k2 * 2] =
        pack2bf(Vs[k2 * 2][dim], Vs[k2 * 2 + 1][dim]);
  }
}

// ---------------- bf16 MFMA GEMM, 64x64 tiles, double-buffered --------------
// MODE 0: C = A@B + bias (fp32 out, stride N)
// MODE 2: fused qkv+gate: n<1024 -> Qb bf16; n<2048 -> Kb bf16;
//         n<3072 -> Vf fp32 (L,1024); else GELU(.+bias2) -> bf16 C2 (gate)
template<int BM, int BN, int MODE>
__global__ __launch_bounds__(256, 6) void gemm_mfma(
    const short* __restrict__ A, const short* __restrict__ Bt,
    const float* __restrict__ bias, const float* __restrict__ bias2,
    float* __restrict__ C, short* __restrict__ C2,
    short* __restrict__ QbP, short* __restrict__ KbP,
    int M, int N, int K)
{
  constexpr int LA = BM / 64, LB = BN / 64;      // 16B loads/thread/tile
  constexpr int WM = BM / 2, WN = BN / 2;
  constexpr int MT = WM / 16, NT = WN / 16;
  __shared__ __align__(16) short As[2][BM * 32];
  __shared__ __align__(16) short Bs[2][BN * 32];
  const int tid = threadIdx.x;
  const int w = tid >> 6, lane = tid & 63;
  const int quad = lane >> 4, c = lane & 15;
  const int m0 = blockIdx.y * BM, n0 = blockIdx.x * BN;
  const int wm = (w & 1) * WM, wn = (w >> 1) * WN;
  f4v acc[MT][NT] = {};

  auto stage = [&](int buf, int k0) {
    #pragma unroll
    for (int it = 0; it < LA; ++it) {
      int off = (it * 256 + tid) * 16;
      int row = off >> 6, colh = (off & 63) >> 1;
      __builtin_amdgcn_global_load_lds(
          (const AS1 u32*)(A + (size_t)(m0 + row) * K + k0 + colh),
          (AS3 u32*)(&As[buf][0] + (off >> 1)), 16, 0, 0);
    }
    #pragma unroll
    for (int it = 0; it < LB; ++it) {
      int off = (it * 256 + tid) * 16;
      int row = off >> 6, colh = (off & 63) >> 1;
      __builtin_amdgcn_global_load_lds(
          (const AS1 u32*)(Bt + (size_t)(n0 + row) * K + k0 + colh),
          (AS3 u32*)(&Bs[buf][0] + (off >> 1)), 16, 0, 0);
    }
  };
  stage(0, 0);
  int cur = 0;
  for (int k0 = 0; k0 < K; k0 += 32) {
    __syncthreads();
    if (k0 + 32 < K) stage(cur ^ 1, k0 + 32);
    s8v af[MT], bf[NT];
    #pragma unroll
    for (int mt = 0; mt < MT; ++mt)
      af[mt] = *(s8v*)&As[cur][(wm + mt * 16 + c) * 32 + quad * 8];
    #pragma unroll
    for (int nt = 0; nt < NT; ++nt)
      bf[nt] = *(s8v*)&Bs[cur][(wn + nt * 16 + c) * 32 + quad * 8];
    #pragma unroll
    for (int mt = 0; mt < MT; ++mt)
      #pragma unroll
      for (int nt = 0; nt < NT; ++nt)
        acc[mt][nt] = __builtin_amdgcn_mfma_f32_16x16x32_bf16(
            af[mt], bf[nt], acc[mt][nt], 0, 0, 0);
    cur ^= 1;
  }
  #pragma unroll
  for (int mt = 0; mt < MT; ++mt)
    #pragma unroll
    for (int r = 0; r < 4; ++r) {
      int m = m0 + wm + mt * 16 + quad * 4 + r;
      #pragma unroll
      for (int nt = 0; nt < NT; ++nt) {
        int n = n0 + wn + nt * 16 + c;
        float v = acc[mt][nt][r];
        if (MODE == 0) {
          C[(size_t)m * N + n] = v + bias[n];
        } else {
          if (n < 2048) {
            float v2 = v + bias[n];
            int hh = (n >> 6) & 15, ee = n & 63;
            short* dst = (n < 1024) ? QbP : KbP;
            dst[((size_t)hh * 2048 + m) * 64 + ee] = f2bf(v2);
          } else if (n < 3072) {
            C[(size_t)m * 1024 + (n - 2048)] = v + bias[n];
          } else {
            float t = v + bias2[n - 3072];
            t = 0.5f * t * (1.0f + erff(t * 0.70710678118654752f));
            C2[(size_t)m * 512 + (n - 3072)] = f2bf(t);
          }
        }
      }
    }
}

// ---------------- flash attention, key-split, un-normalized partials --------
__global__ __launch_bounds__(256) void attn_mfma(
    const short* __restrict__ Qb, const short* __restrict__ Kb,
    const short* __restrict__ Vtb, float* __restrict__ O0,
    float* __restrict__ O1, float* __restrict__ ml)
{
  const int bid = blockIdx.x;
  int h, qt, ts, te;
  float *Odst, *mdst, *ldst;
  if (bid < 512) {
    qt = 31 - (bid >> 5);
    int r = bid & 31; h = r >> 1;
    int n = qt + 1, n2 = (n + 1) >> 1;
    if ((r & 1) == 0) {
      ts = 0; te = n2;
      int s = h * 32 + qt;
      Odst = O0 + (size_t)s * 4096; mdst = ml + s * 64; ldst = ml + 32768 + s * 64;
    } else {
      ts = n2; te = n;
      int s = h * 16 + (qt - 16);
      Odst = O1 + (size_t)s * 4096; mdst = ml + 65536 + s * 64; ldst = ml + 81920 + s * 64;
    }
  } else {
    int r = bid - 512; qt = 15 - (r >> 4); h = r & 15; ts = 0; te = qt + 1;
    int s = h * 32 + qt;
    Odst = O0 + (size_t)s * 4096; mdst = ml + s * 64; ldst = ml + 32768 + s * 64;
  }
  const int q0 = qt * 64;
  const int tid = threadIdx.x;
  const int w = tid >> 6, lane = tid & 63;
  const int quad = lane >> 4, c = lane & 15;

  __shared__ __align__(16) char smem[27648];
  short* Ks = (short*)smem;
  short* Vt = Ks + 4608;
  short* Ps = Vt + 4608;
  float* Ob = (float*)smem;

  const int qrow = q0 + w * 16 + c;
  s8v qf[2];
  qf[0] = *(const s8v*)(Qb + ((size_t)h * 2048 + qrow) * 64 + quad * 8);
  qf[1] = *(const s8v*)(Qb + ((size_t)h * 2048 + qrow) * 64 + 32 + quad * 8);

  const int srow = tid >> 3, sc = (tid & 7) * 8;
  int4 pk0, pk1, pv0, pv1;
  auto load_tile = [&](int t0) {
    const short* kbase = Kb + ((size_t)h * 2048 + t0 * 64) * 64;
    const short* vbase = Vtb + (size_t)h * 64 * 2048 + t0 * 64;
    pk0 = *(const int4*)(kbase + (size_t)srow * 64 + sc);
    pk1 = *(const int4*)(kbase + (size_t)(srow + 32) * 64 + sc);
    pv0 = *(const int4*)(vbase + (size_t)srow * 2048 + sc);
    pv1 = *(const int4*)(vbase + (size_t)(srow + 32) * 2048 + sc);
  };
  load_tile(ts);

  f4v o_acc[4] = {};
  float m = -1e30f, l = 0.f;

  for (int t0 = ts; t0 < te; ++t0) {
    __syncthreads();
    *(int4*)&Ks[srow * 72 + sc] = pk0;
    *(int4*)&Ks[(srow + 32) * 72 + sc] = pk1;
    *(int4*)&Vt[srow * 72 + sc] = pv0;
    *(int4*)&Vt[(srow + 32) * 72 + sc] = pv1;
    __syncthreads();
    if (t0 + 1 < te) load_tile(t0 + 1);

    f4v s_acc[4] = {};
    #pragma unroll
    for (int kt = 0; kt < 4; ++kt) {
      #pragma unroll
      for (int kc = 0; kc < 2; ++kc) {
        s8v kf = *(s8v*)&Ks[(kt * 16 + c) * 72 + kc * 32 + quad * 8];
        s_acc[kt] = __builtin_amdgcn_mfma_f32_16x16x32_bf16(kf, qf[kc], s_acc[kt], 0, 0, 0);
      }
    }
    float sv[4][4];
    bool full = (t0 * 64 + 63) <= (q0 + w * 16);
    #pragma unroll
    for (int kt = 0; kt < 4; ++kt)
      #pragma unroll
      for (int r = 0; r < 4; ++r) {
        float s = s_acc[kt][r] * 0.125f;
        if (!full) {
          int key = t0 * 64 + kt * 16 + quad * 4 + r;
          s = (key <= qrow) ? s : -1e30f;
        }
        sv[kt][r] = s;
      }
    float mloc = -1e30f;
    #pragma unroll
    for (int kt = 0; kt < 4; ++kt)
      #pragma unroll
      for (int r = 0; r < 4; ++r) mloc = fmaxf(mloc, sv[kt][r]);
    mloc = fmaxf(mloc, __shfl_xor(mloc, 16));
    mloc = fmaxf(mloc, __shfl_xor(mloc, 32));
    float mnew = fmaxf(fmaxf(m, mloc), -1e20f);
    float alpha = __expf(m - mnew);
    m = mnew;
    float p[4][4], ls = 0.f;
    #pragma unroll
    for (int kt = 0; kt < 4; ++kt)
      #pragma unroll
      for (int r = 0; r < 4; ++r) { p[kt][r] = __expf(sv[kt][r] - mnew); ls += p[kt][r]; }
    ls += __shfl_xor(ls, 16);
    ls += __shfl_xor(ls, 32);
    l = l * alpha + ls;
    #pragma unroll
    for (int mt = 0; mt < 4; ++mt)
      #pragma unroll
      for (int r = 0; r < 4; ++r) o_acc[mt][r] *= alpha;
    short* Pw = Ps + w * 1152;
    #pragma unroll
    for (int kt = 0; kt < 4; ++kt) {
      *(int*)&Pw[c * 72 + kt * 16 + quad * 4]     = pack2bf(p[kt][0], p[kt][1]);
      *(int*)&Pw[c * 72 + kt * 16 + quad * 4 + 2] = pack2bf(p[kt][2], p[kt][3]);
    }
    #pragma unroll
    for (int kc2 = 0; kc2 < 2; ++kc2) {
      s8v pf = *(s8v*)&Pw[c * 72 + kc2 * 32 + quad * 8];
      #pragma unroll
      for (int mt = 0; mt < 4; ++mt) {
        s8v vf = *(s8v*)&Vt[(mt * 16 + c) * 72 + kc2 * 32 + quad * 8];
        o_acc[mt] = __builtin_amdgcn_mfma_f32_16x16x32_bf16(vf, pf, o_acc[mt], 0, 0, 0);
      }
    }
  }

  __syncthreads();
  #pragma unroll
  for (int mt = 0; mt < 4; ++mt)
    #pragma unroll
    for (int r = 0; r < 4; ++r)
      Ob[(w * 16 + c) * 66 + mt * 16 + quad * 4 + r] = o_acc[mt][r];
  if (quad == 0) { mdst[w * 16 + c] = m; ldst[w * 16 + c] = l; }
  __syncthreads();
  for (int i = tid; i < 4096; i += 256)
    Odst[i] = Ob[(i >> 6) * 66 + (i & 63)];
}

// ---------------- merge partials + gate + combine -> ycb bf16 (L,D) ---------
__global__ __launch_bounds__(256) void attn_merge(
    const float* __restrict__ O0, const float* __restrict__ O1,
    const float* __restrict__ ml, const float* __restrict__ ystp,
    const float* __restrict__ alpha, short* __restrict__ ycb)
{
  int bid = blockIdx.x;
  int h = bid >> 5, qt = bid & 31;
  int slot0 = h * 32 + qt;
  int tid = threadIdx.x;
  for (int it = 0; it < 16; ++it) {
    int idx = it * 256 + tid;
    int q = idx >> 6, e = idx & 63;
    int gq = qt * 64 + q;
    float oo = O0[(size_t)slot0 * 4096 + idx];
    float m0v = ml[slot0 * 64 + q], l0v = ml[32768 + slot0 * 64 + q];
    float ll;
    if (qt >= 16) {
      int slot1 = h * 16 + (qt - 16);
      float o1 = O1[(size_t)slot1 * 4096 + idx];
      float m1v = ml[65536 + slot1 * 64 + q], l1v = ml[81920 + slot1 * 64 + q];
      float ms = fmaxf(m0v, m1v);
      float w0 = __expf(m0v - ms), w1 = __expf(m1v - ms);
      oo = oo * w0 + o1 * w1;
      ll = l0v * w0 + l1v * w1;
    } else {
      ll = l0v;
    }
    float ys = oo / ll;
    float a = alpha[gq * 16 + h];
    float yst = ystp[((size_t)h * 2048 + gq) * 64 + e];
    ycb[(size_t)gq * 1024 + h * 64 + e] = f2bf(a * ys + (1.f - a) * yst);
  }
}

// ---------------- STP branch (bf16 K/Q inputs, fp32 V) ----------------------
__global__ __launch_bounds__(256) void stp_local(const float* __restrict__ Vf,
    const short* __restrict__ Kb, const float* __restrict__ Lam,
    const float* __restrict__ Gam, float* __restrict__ states)
{
  int c = blockIdx.x, h = blockIdx.y;
  int tid = threadIdx.x;
  int i = tid >> 2, j0 = (tid & 3) * 16;
  __shared__ float Kc[64][64];
  __shared__ float Vc[64][64];
  for (int idx = tid; idx < 1024; idx += 256) {
    int t = idx >> 4, e4 = (idx & 15) * 4;
    short4 ks = *(const short4*)(Kb + ((size_t)h * 2048 + c * 64 + t) * 64 + e4);
    Kc[t][e4]     = bf2f(ks.x) * 0.125f;
    Kc[t][e4 + 1] = bf2f(ks.y) * 0.125f;
    Kc[t][e4 + 2] = bf2f(ks.z) * 0.125f;
    Kc[t][e4 + 3] = bf2f(ks.w) * 0.125f;
    float4 vv = *(const float4*)(Vf + (size_t)(c * 64 + t) * 1024 + h * 64 + e4);
    Vc[t][e4] = vv.x; Vc[t][e4 + 1] = vv.y; Vc[t][e4 + 2] = vv.z; Vc[t][e4 + 3] = vv.w;
  }
  float r[16], g[16], s[16];
  #pragma unroll
  for (int e = 0; e < 16; ++e) {
    int idx = h * 4096 + i * 64 + j0 + e;
    r[e] = 1.f / (1.f + expf(Lam[idx]));
    g[e] = Gam[idx];
    s[e] = 0.f;
  }
  __syncthreads();
  for (int t = 0; t < 64; ++t) {
    float v = Vc[t][i];
    #pragma unroll
    for (int e = 0; e < 16; ++e)
      s[e] = r[e] * s[e] + g[e] * (v * Kc[t][j0 + e]);
  }
  #pragma unroll
  for (int e = 0; e < 16; ++e)
    states[((size_t)h * 32 + c) * 4096 + i * 64 + j0 + e] = s[e];
}

__global__ __launch_bounds__(256) void stp_scan(const float* __restrict__ Lam,
                                                float* __restrict__ states)
{
  int gid = blockIdx.x * 256 + threadIdx.x;
  float r = 1.f / (1.f + expf(Lam[gid]));
  float r64 = r;
  #pragma unroll
  for (int q = 0; q < 6; ++q) r64 *= r64;
  int h = gid >> 12, low = gid & 4095;
  float acc = 0.f;
  for (int c = 0; c < 32; ++c) {
    size_t idx = ((size_t)h * 32 + c) * 4096 + low;
    float dloc = states[idx];
    states[idx] = acc;
    acc = r64 * acc + dloc;
  }
}

__global__ __launch_bounds__(256) void stp_out(const float* __restrict__ Vf,
    const short* __restrict__ Kb, const short* __restrict__ Qb,
    const float* __restrict__ Lam, const float* __restrict__ Gam,
    const float* __restrict__ Wst, const float* __restrict__ states,
    float* __restrict__ ystp)
{
  int c = blockIdx.x, h = blockIdx.y;
  int tid = threadIdx.x;
  int i = tid >> 2, j0 = (tid & 3) * 16;
  __shared__ float Kc[64][64];
  __shared__ float Vc[64][64];
  __shared__ float Qc[64][64];
  for (int idx = tid; idx < 1024; idx += 256) {
    int t = idx >> 4, e4 = (idx & 15) * 4;
    size_t bo = ((size_t)h * 2048 + c * 64 + t) * 64 + e4;
    short4 ks = *(const short4*)(Kb + bo);
    short4 qs = *(const short4*)(Qb + bo);
    Kc[t][e4]     = bf2f(ks.x) * 0.125f;
    Kc[t][e4 + 1] = bf2f(ks.y) * 0.125f;
    Kc[t][e4 + 2] = bf2f(ks.z) * 0.125f;
    Kc[t][e4 + 3] = bf2f(ks.w) * 0.125f;
    Qc[t][e4]     = bf2f(qs.x);
    Qc[t][e4 + 1] = bf2f(qs.y);
    Qc[t][e4 + 2] = bf2f(qs.z);
    Qc[t][e4 + 3] = bf2f(qs.w);
    float4 vv = *(const float4*)(Vf + (size_t)(c * 64 + t) * 1024 + h * 64 + e4);
    Vc[t][e4] = vv.x; Vc[t][e4 + 1] = vv.y; Vc[t][e4 + 2] = vv.z; Vc[t][e4 + 3] = vv.w;
  }
  float r[16], g[16], s[16], w[16];
  #pragma unroll
  for (int e = 0; e < 16; ++e) {
    int idx = h * 4096 + i * 64 + j0 + e;
    r[e] = 1.f / (1.f + expf(Lam[idx]));
    g[e] = Gam[idx];
    w[e] = Wst[idx];
    s[e] = states[((size_t)h * 32 + c) * 4096 + i * 64 + j0 + e];
  }
  __syncthreads();
  for (int t = 0; t < 64; ++t) {
    float v = Vc[t][i];
    float y = 0.f;
    #pragma unroll
    for (int e = 0; e < 16; ++e) {
      s[e] = r[e] * s[e] + g[e] * (v * Kc[t][j0 + e]);
      y += (w[e] + s[e]) * Qc[t][j0 + e];
    }
    y += __shfl_xor(y, 1);
    y += __shfl_xor(y, 2);
    if ((tid & 3) == 0)
      ystp[((size_t)h * L_SEQ + c * 64 + t) * 64 + i] = y;
  }
}

// ---------------- gate tail (bf16 g) ----------------------------------------
__global__ __launch_bounds__(256) void gate2_kernel(const short* __restrict__ g_bf,
    const float* __restrict__ w2, const float* __restrict__ b2,
    float* __restrict__ alpha)
{
  int gid = blockIdx.x * 256 + threadIdx.x;
  int l = gid >> 4, h = gid & 15;
  float acc = b2[h];
  const short* grow = g_bf + (size_t)l * 512;
  for (int c2 = 0; c2 < 512; c2 += 2) {
    u32 pk = *(const u32*)(grow + c2);
    float g0 = __uint_as_float(pk << 16);
    float g1 = __uint_as_float(pk & 0xffff0000u);
    acc += g0 * w2[c2 * 16 + h] + g1 * w2[(c2 + 1) * 16 + h];
  }
  alpha[gid] = 1.f / (1.f + expf(-acc));
}

extern "C" void kernel_launch(void* const* d_in, const int* in_sizes, int n_in,
                              void* d_out, int out_size, void* d_ws, size_t ws_size,
                              hipStream_t stream) {
  (void)in_sizes; (void)n_in; (void)out_size; (void)ws_size;
  const float* x      = (const float*)d_in[0];
  const float* Wqkv_w = (const float*)d_in[1];
  const float* Wqkv_b = (const float*)d_in[2];
  const float* out_w  = (const float*)d_in[3];
  const float* out_b  = (const float*)d_in[4];
  const float* W_st   = (const float*)d_in[5];
  const float* Lam    = (const float*)d_in[6];
  const float* Gam    = (const float*)d_in[7];
  const float* gw1    = (const float*)d_in[8];
  const float* gb1    = (const float*)d_in[9];
  const float* gw2    = (const float*)d_in[10];
  const float* gb2    = (const float*)d_in[11];

  float* ws     = (float*)d_ws;
  float* Vf     = ws;                        // (L,1024) fp32        2097152 f
  float* O0buf  = ws + 2097152;              // 512 slots x 4096     2097152 f
  float* ystp   = ws + 4194304;              //                      2097152 f
  float* states = ws + 6291456;              // stp; later O1 + ycb  2097152 f
  float* ovl    = ws + 8388608;              // overlay span         3670016 f
  float* alpha  = ws + 12058624;             //                        32768 f
  float* ml     = ws + 12091392;             //                        98304 f
  short* Qb     = (short*)(ws + 12189696);   // (H,L,64) bf16        1048576 f
  short* Kb     = Qb + 2097152;              //                      1048576 f
  // phase-1 overlay
  short* xb     = (short*)ovl;
  short* wt_buf = (short*)(ovl + 1048576);
  short* g_bf   = (short*)(ovl + 2883584);
  // phase-2/3 overlay
  short* Vtb    = (short*)ovl;
  short* wtO    = (short*)ovl;
  float* O1buf  = states;
  short* ycb    = (short*)(states + 1048576);

  // phase 1: fused qkv+gate projection (emits Qb/Kb bf16, Vf fp32, g_bf)
  conv_x<<<dim3(2048), 256, 0, stream>>>(x, xb);
  transpose_conv<<<dim3(96, 32), 256, 0, stream>>>(Wqkv_w, wt_buf, 1024, 3072);
  transpose_conv<<<dim3(16, 32), 256, 0, stream>>>(gw1, wt_buf + 3072 * 1024, 1024, 512);
  gemm_mfma<64, 64, 2><<<dim3(56, 32), 256, 0, stream>>>(
      xb, wt_buf, Wqkv_b, gb1, Vf, g_bf, Qb, Kb, 2048, 3584, 1024);
  gate2_kernel<<<dim3(128), 256, 0, stream>>>(g_bf, gw2, gb2, alpha);
  // STP branch
  stp_local<<<dim3(32, 16), 256, 0, stream>>>(Vf, Kb, Lam, Gam, states);
  stp_scan<<<dim3(256), 256, 0, stream>>>(Lam, states);
  stp_out<<<dim3(32, 16), 256, 0, stream>>>(Vf, Kb, Qb, Lam, Gam, W_st, states, ystp);
  // phase 2: attention (key-split) + merge/gate/combine
  conv_vt<<<dim3(32, 16), 256, 0, stream>>>(Vf, Vtb);
  attn_mfma<<<dim3(768), 256, 0, stream>>>(Qb, Kb, Vtb, O0buf, O1buf, ml);
  attn_merge<<<dim3(512), 256, 0, stream>>>(O0buf, O1buf, ml, ystp, alpha, ycb);
  // phase 3: out projection (64x64 tiles, 512 blocks)
  transpose_conv<<<dim3(32, 32), 256, 0, stream>>>(out_w, wtO, 1024, 1024);
  gemm_mfma<64, 64, 0><<<dim3(16, 32), 256, 0, stream>>>(
      ycb, wtO, out_b, nullptr, (float*)d_out, nullptr, nullptr, nullptr, 2048, 1024, 1024);
}

// Round 9
// 257.500 us; speedup vs baseline: 1.0788x; 1.0257x over previous
//
#include <hip/hip_runtime.h>
#include <hip/hip_bf16.h>

#define L_SEQ 2048
#define DMODEL 1024
#define NHEAD 16
#define DHEAD 64
#define D3 3072

typedef __attribute__((ext_vector_type(8))) short s8v;   // 8 bf16 (4 VGPRs)
typedef __attribute__((ext_vector_type(4))) float f4v;   // MFMA acc
typedef unsigned int u32;
#define AS1 __attribute__((address_space(1)))
#define AS3 __attribute__((address_space(3)))

__device__ __forceinline__ short f2bf(float f) {
  __hip_bfloat16 h = __float2bfloat16(f);
  return *reinterpret_cast<short*>(&h);
}
__device__ __forceinline__ float bf2f(short s) {
  return __uint_as_float(((u32)(unsigned short)s) << 16);
}
__device__ __forceinline__ int pack2bf(float lo, float hi) {
  return (int)(((unsigned)(unsigned short)f2bf(hi) << 16) |
               (unsigned)(unsigned short)f2bf(lo));
}

// ---------------- fused prep: x->bf16 + 3 weight transposes -----------------
// blocks [0,2048): conv_x; [2048,5120): Wqkv^T; [5120,5632): gw1^T;
// [5632,6656): out_w^T
__device__ __forceinline__ void transpose32(const float* __restrict__ W,
    short* __restrict__ Wt, int K, int N, int bx, int by, int tid)
{
  __shared__ float T[32][33];
  int col = tid & 31, rb = tid >> 5;
  #pragma unroll
  for (int it = 0; it < 4; ++it) {
    int r = it * 8 + rb;
    T[r][col] = W[(size_t)(by * 32 + r) * N + bx * 32 + col];
  }
  __syncthreads();
  #pragma unroll
  for (int it = 0; it < 4; ++it) {
    int r = it * 8 + rb;
    Wt[(size_t)(bx * 32 + r) * K + by * 32 + col] = f2bf(T[col][r]);
  }
}

__global__ __launch_bounds__(256) void prep_kernel(
    const float* __restrict__ x, short* __restrict__ xb,
    const float* __restrict__ Wqkv_w, const float* __restrict__ gw1,
    const float* __restrict__ out_w, short* __restrict__ wt_buf,
    short* __restrict__ wtO)
{
  int b = blockIdx.x, tid = threadIdx.x;
  if (b < 2048) {
    int i = (b * 256 + tid) * 4;
    float4 v = *(const float4*)(x + i);
    short4 o;
    o.x = f2bf(v.x); o.y = f2bf(v.y); o.z = f2bf(v.z); o.w = f2bf(v.w);
    *(short4*)(xb + i) = o;
  } else if (b < 5120) {
    int r = b - 2048;
    transpose32(Wqkv_w, wt_buf, 1024, 3072, r % 96, r / 96, tid);
  } else if (b < 5632) {
    int r = b - 5120;
    transpose32(gw1, wt_buf + 3072 * 1024, 1024, 512, r % 16, r / 16, tid);
  } else {
    int r = b - 5632;
    transpose32(out_w, wtO, 1024, 1024, r % 32, r / 32, tid);
  }
}

// ---------------- Vf (L,1024) fp32 -> Vtb (H,64,L) bf16 ---------------------
__global__ __launch_bounds__(256) void conv_vt(const float* __restrict__ Vf,
                                               short* __restrict__ Vtb)
{
  int kb = blockIdx.x, h = blockIdx.y;
  int tid = threadIdx.x;
  __shared__ float Vs[64][65];
  for (int idx = tid; idx < 2048; idx += 256) {
    int key = idx >> 5, e2 = idx & 31;
    float2 vv = *(const float2*)(Vf + (size_t)(kb * 64 + key) * 1024 + h * 64 + e2 * 2);
    Vs[key][e2 * 2] = vv.x; Vs[key][e2 * 2 + 1] = vv.y;
  }
  __syncthreads();
  for (int idx = tid; idx < 2048; idx += 256) {
    int dim = idx >> 5, k2 = idx & 31;
    *(int*)&Vtb[((size_t)h * 64 + dim) * 2048 + kb * 64 + k2 * 2] =
        pack2bf(Vs[k2 * 2][dim], Vs[k2 * 2 + 1][dim]);
  }
}

// ---------------- bf16 MFMA GEMM, double-buffered ---------------------------
// MODE 0: C = A@B + bias (fp32 out, stride N)
// MODE 2: fused qkv+gate: n<1024 -> Qb bf16; n<2048 -> Kb bf16;
//         n<3072 -> Vf fp32 (L,1024); else GELU(.+bias2) -> bf16 C2 (gate)
template<int BM, int BN, int MODE>
__global__ __launch_bounds__(256, 6) void gemm_mfma(
    const short* __restrict__ A, const short* __restrict__ Bt,
    const float* __restrict__ bias, const float* __restrict__ bias2,
    float* __restrict__ C, short* __restrict__ C2,
    short* __restrict__ QbP, short* __restrict__ KbP,
    int M, int N, int K)
{
  constexpr int LA = BM / 64, LB = BN / 64;      // 16B loads/thread/tile
  constexpr int WM = BM / 2, WN = BN / 2;
  constexpr int MT = WM / 16, NT = WN / 16;
  __shared__ __align__(16) short As[2][BM * 32];
  __shared__ __align__(16) short Bs[2][BN * 32];
  const int tid = threadIdx.x;
  const int w = tid >> 6, lane = tid & 63;
  const int quad = lane >> 4, c = lane & 15;
  const int m0 = blockIdx.y * BM, n0 = blockIdx.x * BN;
  const int wm = (w & 1) * WM, wn = (w >> 1) * WN;
  f4v acc[MT][NT] = {};

  auto stage = [&](int buf, int k0) {
    #pragma unroll
    for (int it = 0; it < LA; ++it) {
      int off = (it * 256 + tid) * 16;
      int row = off >> 6, colh = (off & 63) >> 1;
      __builtin_amdgcn_global_load_lds(
          (const AS1 u32*)(A + (size_t)(m0 + row) * K + k0 + colh),
          (AS3 u32*)(&As[buf][0] + (off >> 1)), 16, 0, 0);
    }
    #pragma unroll
    for (int it = 0; it < LB; ++it) {
      int off = (it * 256 + tid) * 16;
      int row = off >> 6, colh = (off & 63) >> 1;
      __builtin_amdgcn_global_load_lds(
          (const AS1 u32*)(Bt + (size_t)(n0 + row) * K + k0 + colh),
          (AS3 u32*)(&Bs[buf][0] + (off >> 1)), 16, 0, 0);
    }
  };
  stage(0, 0);
  int cur = 0;
  for (int k0 = 0; k0 < K; k0 += 32) {
    __syncthreads();
    if (k0 + 32 < K) stage(cur ^ 1, k0 + 32);
    s8v af[MT], bf[NT];
    #pragma unroll
    for (int mt = 0; mt < MT; ++mt)
      af[mt] = *(s8v*)&As[cur][(wm + mt * 16 + c) * 32 + quad * 8];
    #pragma unroll
    for (int nt = 0; nt < NT; ++nt)
      bf[nt] = *(s8v*)&Bs[cur][(wn + nt * 16 + c) * 32 + quad * 8];
    #pragma unroll
    for (int mt = 0; mt < MT; ++mt)
      #pragma unroll
      for (int nt = 0; nt < NT; ++nt)
        acc[mt][nt] = __builtin_amdgcn_mfma_f32_16x16x32_bf16(
            af[mt], bf[nt], acc[mt][nt], 0, 0, 0);
    cur ^= 1;
  }
  #pragma unroll
  for (int mt = 0; mt < MT; ++mt)
    #pragma unroll
    for (int r = 0; r < 4; ++r) {
      int m = m0 + wm + mt * 16 + quad * 4 + r;
      #pragma unroll
      for (int nt = 0; nt < NT; ++nt) {
        int n = n0 + wn + nt * 16 + c;
        float v = acc[mt][nt][r];
        if (MODE == 0) {
          C[(size_t)m * N + n] = v + bias[n];
        } else {
          if (n < 2048) {
            float v2 = v + bias[n];
            int hh = (n >> 6) & 15, ee = n & 63;
            short* dst = (n < 1024) ? QbP : KbP;
            dst[((size_t)hh * 2048 + m) * 64 + ee] = f2bf(v2);
          } else if (n < 3072) {
            C[(size_t)m * 1024 + (n - 2048)] = v + bias[n];
          } else {
            float t = v + bias2[n - 3072];
            t = 0.5f * t * (1.0f + erff(t * 0.70710678118654752f));
            C2[(size_t)m * 512 + (n - 3072)] = f2bf(t);
          }
        }
      }
    }
}

// ---------------- flash attention, key-split, un-normalized partials --------
__global__ __launch_bounds__(256) void attn_mfma(
    const short* __restrict__ Qb, const short* __restrict__ Kb,
    const short* __restrict__ Vtb, float* __restrict__ O0,
    float* __restrict__ O1, float* __restrict__ ml)
{
  const int bid = blockIdx.x;
  int h, qt, ts, te;
  float *Odst, *mdst, *ldst;
  if (bid < 512) {
    qt = 31 - (bid >> 5);
    int r = bid & 31; h = r >> 1;
    int n = qt + 1, n2 = (n + 1) >> 1;
    if ((r & 1) == 0) {
      ts = 0; te = n2;
      int s = h * 32 + qt;
      Odst = O0 + (size_t)s * 4096; mdst = ml + s * 64; ldst = ml + 32768 + s * 64;
    } else {
      ts = n2; te = n;
      int s = h * 16 + (qt - 16);
      Odst = O1 + (size_t)s * 4096; mdst = ml + 65536 + s * 64; ldst = ml + 81920 + s * 64;
    }
  } else {
    int r = bid - 512; qt = 15 - (r >> 4); h = r & 15; ts = 0; te = qt + 1;
    int s = h * 32 + qt;
    Odst = O0 + (size_t)s * 4096; mdst = ml + s * 64; ldst = ml + 32768 + s * 64;
  }
  const int q0 = qt * 64;
  const int tid = threadIdx.x;
  const int w = tid >> 6, lane = tid & 63;
  const int quad = lane >> 4, c = lane & 15;

  __shared__ __align__(16) char smem[27648];
  short* Ks = (short*)smem;
  short* Vt = Ks + 4608;
  short* Ps = Vt + 4608;
  float* Ob = (float*)smem;

  const int qrow = q0 + w * 16 + c;
  s8v qf[2];
  qf[0] = *(const s8v*)(Qb + ((size_t)h * 2048 + qrow) * 64 + quad * 8);
  qf[1] = *(const s8v*)(Qb + ((size_t)h * 2048 + qrow) * 64 + 32 + quad * 8);

  const int srow = tid >> 3, sc = (tid & 7) * 8;
  int4 pk0, pk1, pv0, pv1;
  auto load_tile = [&](int t0) {
    const short* kbase = Kb + ((size_t)h * 2048 + t0 * 64) * 64;
    const short* vbase = Vtb + (size_t)h * 64 * 2048 + t0 * 64;
    pk0 = *(const int4*)(kbase + (size_t)srow * 64 + sc);
    pk1 = *(const int4*)(kbase + (size_t)(srow + 32) * 64 + sc);
    pv0 = *(const int4*)(vbase + (size_t)srow * 2048 + sc);
    pv1 = *(const int4*)(vbase + (size_t)(srow + 32) * 2048 + sc);
  };
  load_tile(ts);

  f4v o_acc[4] = {};
  float m = -1e30f, l = 0.f;

  for (int t0 = ts; t0 < te; ++t0) {
    __syncthreads();
    *(int4*)&Ks[srow * 72 + sc] = pk0;
    *(int4*)&Ks[(srow + 32) * 72 + sc] = pk1;
    *(int4*)&Vt[srow * 72 + sc] = pv0;
    *(int4*)&Vt[(srow + 32) * 72 + sc] = pv1;
    __syncthreads();
    if (t0 + 1 < te) load_tile(t0 + 1);

    f4v s_acc[4] = {};
    #pragma unroll
    for (int kt = 0; kt < 4; ++kt) {
      #pragma unroll
      for (int kc = 0; kc < 2; ++kc) {
        s8v kf = *(s8v*)&Ks[(kt * 16 + c) * 72 + kc * 32 + quad * 8];
        s_acc[kt] = __builtin_amdgcn_mfma_f32_16x16x32_bf16(kf, qf[kc], s_acc[kt], 0, 0, 0);
      }
    }
    float sv[4][4];
    bool full = (t0 * 64 + 63) <= (q0 + w * 16);
    #pragma unroll
    for (int kt = 0; kt < 4; ++kt)
      #pragma unroll
      for (int r = 0; r < 4; ++r) {
        float s = s_acc[kt][r] * 0.125f;
        if (!full) {
          int key = t0 * 64 + kt * 16 + quad * 4 + r;
          s = (key <= qrow) ? s : -1e30f;
        }
        sv[kt][r] = s;
      }
    float mloc = -1e30f;
    #pragma unroll
    for (int kt = 0; kt < 4; ++kt)
      #pragma unroll
      for (int r = 0; r < 4; ++r) mloc = fmaxf(mloc, sv[kt][r]);
    mloc = fmaxf(mloc, __shfl_xor(mloc, 16));
    mloc = fmaxf(mloc, __shfl_xor(mloc, 32));
    float mnew = fmaxf(fmaxf(m, mloc), -1e20f);
    float alpha = __expf(m - mnew);
    m = mnew;
    float p[4][4], ls = 0.f;
    #pragma unroll
    for (int kt = 0; kt < 4; ++kt)
      #pragma unroll
      for (int r = 0; r < 4; ++r) { p[kt][r] = __expf(sv[kt][r] - mnew); ls += p[kt][r]; }
    ls += __shfl_xor(ls, 16);
    ls += __shfl_xor(ls, 32);
    l = l * alpha + ls;
    #pragma unroll
    for (int mt = 0; mt < 4; ++mt)
      #pragma unroll
      for (int r = 0; r < 4; ++r) o_acc[mt][r] *= alpha;
    short* Pw = Ps + w * 1152;
    #pragma unroll
    for (int kt = 0; kt < 4; ++kt) {
      *(int*)&Pw[c * 72 + kt * 16 + quad * 4]     = pack2bf(p[kt][0], p[kt][1]);
      *(int*)&Pw[c * 72 + kt * 16 + quad * 4 + 2] = pack2bf(p[kt][2], p[kt][3]);
    }
    #pragma unroll
    for (int kc2 = 0; kc2 < 2; ++kc2) {
      s8v pf = *(s8v*)&Pw[c * 72 + kc2 * 32 + quad * 8];
      #pragma unroll
      for (int mt = 0; mt < 4; ++mt) {
        s8v vf = *(s8v*)&Vt[(mt * 16 + c) * 72 + kc2 * 32 + quad * 8];
        o_acc[mt] = __builtin_amdgcn_mfma_f32_16x16x32_bf16(vf, pf, o_acc[mt], 0, 0, 0);
      }
    }
  }

  __syncthreads();
  #pragma unroll
  for (int mt = 0; mt < 4; ++mt)
    #pragma unroll
    for (int r = 0; r < 4; ++r)
      Ob[(w * 16 + c) * 66 + mt * 16 + quad * 4 + r] = o_acc[mt][r];
  if (quad == 0) { mdst[w * 16 + c] = m; ldst[w * 16 + c] = l; }
  __syncthreads();
  for (int i = tid; i < 4096; i += 256)
    Odst[i] = Ob[(i >> 6) * 66 + (i & 63)];
}

// ---------------- merge partials + gate + combine -> ycb bf16 (L,D) ---------
__global__ __launch_bounds__(256) void attn_merge(
    const float* __restrict__ O0, const float* __restrict__ O1,
    const float* __restrict__ ml, const float* __restrict__ ystp,
    const float* __restrict__ alpha, short* __restrict__ ycb)
{
  int bid = blockIdx.x;
  int h = bid >> 5, qt = bid & 31;
  int slot0 = h * 32 + qt;
  int tid = threadIdx.x;
  for (int it = 0; it < 16; ++it) {
    int idx = it * 256 + tid;
    int q = idx >> 6, e = idx & 63;
    int gq = qt * 64 + q;
    float oo = O0[(size_t)slot0 * 4096 + idx];
    float m0v = ml[slot0 * 64 + q], l0v = ml[32768 + slot0 * 64 + q];
    float ll;
    if (qt >= 16) {
      int slot1 = h * 16 + (qt - 16);
      float o1 = O1[(size_t)slot1 * 4096 + idx];
      float m1v = ml[65536 + slot1 * 64 + q], l1v = ml[81920 + slot1 * 64 + q];
      float ms = fmaxf(m0v, m1v);
      float w0 = __expf(m0v - ms), w1 = __expf(m1v - ms);
      oo = oo * w0 + o1 * w1;
      ll = l0v * w0 + l1v * w1;
    } else {
      ll = l0v;
    }
    float ys = oo / ll;
    float a = alpha[gq * 16 + h];
    float yst = ystp[((size_t)h * 2048 + gq) * 64 + e];
    ycb[(size_t)gq * 1024 + h * 64 + e] = f2bf(a * ys + (1.f - a) * yst);
  }
}

// ---------------- STP branch (bf16 K/Q inputs, fp32 V) ----------------------
__global__ __launch_bounds__(256) void stp_local(const float* __restrict__ Vf,
    const short* __restrict__ Kb, const float* __restrict__ Lam,
    const float* __restrict__ Gam, float* __restrict__ states)
{
  int c = blockIdx.x, h = blockIdx.y;
  int tid = threadIdx.x;
  int i = tid >> 2, j0 = (tid & 3) * 16;
  __shared__ float Kc[64][64];
  __shared__ float Vc[64][64];
  for (int idx = tid; idx < 1024; idx += 256) {
    int t = idx >> 4, e4 = (idx & 15) * 4;
    short4 ks = *(const short4*)(Kb + ((size_t)h * 2048 + c * 64 + t) * 64 + e4);
    Kc[t][e4]     = bf2f(ks.x) * 0.125f;
    Kc[t][e4 + 1] = bf2f(ks.y) * 0.125f;
    Kc[t][e4 + 2] = bf2f(ks.z) * 0.125f;
    Kc[t][e4 + 3] = bf2f(ks.w) * 0.125f;
    float4 vv = *(const float4*)(Vf + (size_t)(c * 64 + t) * 1024 + h * 64 + e4);
    Vc[t][e4] = vv.x; Vc[t][e4 + 1] = vv.y; Vc[t][e4 + 2] = vv.z; Vc[t][e4 + 3] = vv.w;
  }
  float r[16], g[16], s[16];
  #pragma unroll
  for (int e = 0; e < 16; ++e) {
    int idx = h * 4096 + i * 64 + j0 + e;
    r[e] = 1.f / (1.f + expf(Lam[idx]));
    g[e] = Gam[idx];
    s[e] = 0.f;
  }
  __syncthreads();
  for (int t = 0; t < 64; ++t) {
    float v = Vc[t][i];
    #pragma unroll
    for (int e = 0; e < 16; ++e)
      s[e] = r[e] * s[e] + g[e] * (v * Kc[t][j0 + e]);
  }
  #pragma unroll
  for (int e = 0; e < 16; ++e)
    states[((size_t)h * 32 + c) * 4096 + i * 64 + j0 + e] = s[e];
}

__global__ __launch_bounds__(256) void stp_scan(const float* __restrict__ Lam,
                                                float* __restrict__ states)
{
  int gid = blockIdx.x * 256 + threadIdx.x;
  float r = 1.f / (1.f + expf(Lam[gid]));
  float r64 = r;
  #pragma unroll
  for (int q = 0; q < 6; ++q) r64 *= r64;
  int h = gid >> 12, low = gid & 4095;
  float acc = 0.f;
  for (int c = 0; c < 32; ++c) {
    size_t idx = ((size_t)h * 32 + c) * 4096 + low;
    float dloc = states[idx];
    states[idx] = acc;
    acc = r64 * acc + dloc;
  }
}

__global__ __launch_bounds__(256) void stp_out(const float* __restrict__ Vf,
    const short* __restrict__ Kb, const short* __restrict__ Qb,
    const float* __restrict__ Lam, const float* __restrict__ Gam,
    const float* __restrict__ Wst, const float* __restrict__ states,
    float* __restrict__ ystp)
{
  int c = blockIdx.x, h = blockIdx.y;
  int tid = threadIdx.x;
  int i = tid >> 2, j0 = (tid & 3) * 16;
  __shared__ float Kc[64][64];
  __shared__ float Vc[64][64];
  __shared__ float Qc[64][64];
  for (int idx = tid; idx < 1024; idx += 256) {
    int t = idx >> 4, e4 = (idx & 15) * 4;
    size_t bo = ((size_t)h * 2048 + c * 64 + t) * 64 + e4;
    short4 ks = *(const short4*)(Kb + bo);
    short4 qs = *(const short4*)(Qb + bo);
    Kc[t][e4]     = bf2f(ks.x) * 0.125f;
    Kc[t][e4 + 1] = bf2f(ks.y) * 0.125f;
    Kc[t][e4 + 2] = bf2f(ks.z) * 0.125f;
    Kc[t][e4 + 3] = bf2f(ks.w) * 0.125f;
    Qc[t][e4]     = bf2f(qs.x);
    Qc[t][e4 + 1] = bf2f(qs.y);
    Qc[t][e4 + 2] = bf2f(qs.z);
    Qc[t][e4 + 3] = bf2f(qs.w);
    float4 vv = *(const float4*)(Vf + (size_t)(c * 64 + t) * 1024 + h * 64 + e4);
    Vc[t][e4] = vv.x; Vc[t][e4 + 1] = vv.y; Vc[t][e4 + 2] = vv.z; Vc[t][e4 + 3] = vv.w;
  }
  float r[16], g[16], s[16], w[16];
  #pragma unroll
  for (int e = 0; e < 16; ++e) {
    int idx = h * 4096 + i * 64 + j0 + e;
    r[e] = 1.f / (1.f + expf(Lam[idx]));
    g[e] = Gam[idx];
    w[e] = Wst[idx];
    s[e] = states[((size_t)h * 32 + c) * 4096 + i * 64 + j0 + e];
  }
  __syncthreads();
  for (int t = 0; t < 64; ++t) {
    float v = Vc[t][i];
    float y = 0.f;
    #pragma unroll
    for (int e = 0; e < 16; ++e) {
      s[e] = r[e] * s[e] + g[e] * (v * Kc[t][j0 + e]);
      y += (w[e] + s[e]) * Qc[t][j0 + e];
    }
    y += __shfl_xor(y, 1);
    y += __shfl_xor(y, 2);
    if ((tid & 3) == 0)
      ystp[((size_t)h * L_SEQ + c * 64 + t) * 64 + i] = y;
  }
}

// ---------------- gate tail (bf16 g) ----------------------------------------
__global__ __launch_bounds__(256) void gate2_kernel(const short* __restrict__ g_bf,
    const float* __restrict__ w2, const float* __restrict__ b2,
    float* __restrict__ alpha)
{
  int gid = blockIdx.x * 256 + threadIdx.x;
  int l = gid >> 4, h = gid & 15;
  float acc = b2[h];
  const short* grow = g_bf + (size_t)l * 512;
  for (int c2 = 0; c2 < 512; c2 += 2) {
    u32 pk = *(const u32*)(grow + c2);
    float g0 = __uint_as_float(pk << 16);
    float g1 = __uint_as_float(pk & 0xffff0000u);
    acc += g0 * w2[c2 * 16 + h] + g1 * w2[(c2 + 1) * 16 + h];
  }
  alpha[gid] = 1.f / (1.f + expf(-acc));
}

extern "C" void kernel_launch(void* const* d_in, const int* in_sizes, int n_in,
                              void* d_out, int out_size, void* d_ws, size_t ws_size,
                              hipStream_t stream) {
  (void)in_sizes; (void)n_in; (void)out_size; (void)ws_size;
  const float* x      = (const float*)d_in[0];
  const float* Wqkv_w = (const float*)d_in[1];
  const float* Wqkv_b = (const float*)d_in[2];
  const float* out_w  = (const float*)d_in[3];
  const float* out_b  = (const float*)d_in[4];
  const float* W_st   = (const float*)d_in[5];
  const float* Lam    = (const float*)d_in[6];
  const float* Gam    = (const float*)d_in[7];
  const float* gw1    = (const float*)d_in[8];
  const float* gb1    = (const float*)d_in[9];
  const float* gw2    = (const float*)d_in[10];
  const float* gb2    = (const float*)d_in[11];

  float* ws     = (float*)d_ws;
  float* Vf     = ws;                        // (L,1024) fp32        2097152 f
  float* O0buf  = ws + 2097152;              // 512 slots x 4096     2097152 f
  float* ystp   = ws + 4194304;              //                      2097152 f
  float* states = ws + 6291456;              // stp; later O1 + ycb  2097152 f
  float* ovl    = ws + 8388608;              // overlay span         3670016 f
  float* alpha  = ws + 12058624;             //                        32768 f
  float* ml     = ws + 12091392;             //                        98304 f
  short* Qb     = (short*)(ws + 12189696);   // (H,L,64) bf16        1048576 f
  short* Kb     = Qb + 2097152;              //                      1048576 f
  short* wtO    = (short*)(ws + 14286848);   // out_w^T bf16          524288 f
  // total 14811136 floats = 59.2 MB
  // phase-1 overlay
  short* xb     = (short*)ovl;
  short* wt_buf = (short*)(ovl + 1048576);
  short* g_bf   = (short*)(ovl + 2883584);
  // phase-2 overlay
  short* Vtb    = (short*)ovl;               // overwrites xb (dead after gemm)
  float* O1buf  = states;
  short* ycb    = (short*)(states + 1048576);

  // phase 0: all conversions/transposes in one launch
  prep_kernel<<<dim3(6656), 256, 0, stream>>>(x, xb, Wqkv_w, gw1, out_w, wt_buf, wtO);
  // phase 1: fused qkv+gate projection (emits Qb/Kb bf16, Vf fp32, g_bf)
  gemm_mfma<128, 64, 2><<<dim3(56, 16), 256, 0, stream>>>(
      xb, wt_buf, Wqkv_b, gb1, Vf, g_bf, Qb, Kb, 2048, 3584, 1024);
  gate2_kernel<<<dim3(128), 256, 0, stream>>>(g_bf, gw2, gb2, alpha);
  // STP branch
  stp_local<<<dim3(32, 16), 256, 0, stream>>>(Vf, Kb, Lam, Gam, states);
  stp_scan<<<dim3(256), 256, 0, stream>>>(Lam, states);
  stp_out<<<dim3(32, 16), 256, 0, stream>>>(Vf, Kb, Qb, Lam, Gam, W_st, states, ystp);
  // phase 2: attention (key-split) + merge/gate/combine
  conv_vt<<<dim3(32, 16), 256, 0, stream>>>(Vf, Vtb);
  attn_mfma<<<dim3(768), 256, 0, stream>>>(Qb, Kb, Vtb, O0buf, O1buf, ml);
  attn_merge<<<dim3(512), 256, 0, stream>>>(O0buf, O1buf, ml, ystp, alpha, ycb);
  // phase 3: out projection (64x64 tiles, 512 blocks)
  gemm_mfma<64, 64, 0><<<dim3(16, 32), 256, 0, stream>>>(
      ycb, wtO, out_b, nullptr, (float*)d_out, nullptr, nullptr, nullptr, 2048, 1024, 1024);
}